// Round 1
// baseline (230.394 us; speedup 1.0000x reference)
//
#include <hip/hip_runtime.h>

// Problem constants
#define NB 4
#define LL 2048
#define EE 512
#define HH 8
#define DD 64

typedef __attribute__((ext_vector_type(8))) short short8;
typedef __attribute__((ext_vector_type(4))) float f32x4;
typedef __bf16 bf16x8 __attribute__((ext_vector_type(8)));

static __device__ __forceinline__ unsigned short f2bf(float f) {
    unsigned u = __builtin_bit_cast(unsigned, f);
    unsigned r = u + 0x7FFFu + ((u >> 16) & 1u);   // RNE
    return (unsigned short)(r >> 16);
}

static __device__ __forceinline__ f32x4 mfma_bf16(short8 a, short8 b, f32x4 c) {
    return __builtin_amdgcn_mfma_f32_16x16x32_bf16(
        __builtin_bit_cast(bf16x8, a), __builtin_bit_cast(bf16x8, b), c, 0, 0, 0);
}

// ---------------------------------------------------------------- K0: Wo -> bf16
__global__ __launch_bounds__(256) void k_cvt(const float* __restrict__ src,
                                             unsigned short* __restrict__ dst, int n) {
    int i = (blockIdx.x * 256 + threadIdx.x) * 4;
    if (i < n) {
        float4 v = *(const float4*)(src + i);
        dst[i + 0] = f2bf(v.x);
        dst[i + 1] = f2bf(v.y);
        dst[i + 2] = f2bf(v.z);
        dst[i + 3] = f2bf(v.w);
    }
}

// ---------------------------------------------------------------- K1: QKV projections
// rows = (n,l,h) flat = N*L*H = 65536, each row is 64 fp32 contiguous.
// Qp/Kp out layout [n,h,l,d] bf16 (Q pre-scaled by 1/sqrt(512)); V out transposed [n,h,d,l].
__global__ __launch_bounds__(256) void k_proj(const float* __restrict__ vals,
                                              const float* __restrict__ keys,
                                              const float* __restrict__ qry,
                                              const float* __restrict__ Wv,
                                              const float* __restrict__ Wk,
                                              const float* __restrict__ Wq,
                                              unsigned short* __restrict__ Qp,
                                              unsigned short* __restrict__ Kp,
                                              unsigned short* __restrict__ VpT) {
    const int tid = threadIdx.x;
    const int w = tid >> 6, ln = tid & 63;
    const int c = ln & 15, g = ln >> 4;

    // B fragments of all three weight matrices (B[k=d][col=o] = W[o][d], contiguous d per lane)
    const float* Ws[3] = {Wv, Wk, Wq};
    short8 wf[3][4][2];
    for (int t = 0; t < 3; ++t)
        for (int nt = 0; nt < 4; ++nt)
            for (int kk = 0; kk < 2; ++kk) {
                const float* p = Ws[t] + (nt * 16 + c) * DD + kk * 32 + g * 8;
                short8 v;
#pragma unroll
                for (int j = 0; j < 8; ++j) v[j] = (short)f2bf(p[j]);
                wf[t][nt][kk] = v;
            }

    const float* Xs[3] = {vals, keys, qry};
    for (int rt = 0; rt < 4; ++rt) {
        const int rbase = blockIdx.x * 256 + rt * 64 + w * 16;
        for (int t = 0; t < 3; ++t) {
            short8 a[2];
            for (int kk = 0; kk < 2; ++kk) {
                const float* p = Xs[t] + (rbase + c) * DD + kk * 32 + g * 8;
                short8 v;
#pragma unroll
                for (int j = 0; j < 8; ++j) v[j] = (short)f2bf(p[j]);
                a[kk] = v;
            }
            for (int nt = 0; nt < 4; ++nt) {
                f32x4 acc = {0.f, 0.f, 0.f, 0.f};
                acc = mfma_bf16(a[0], wf[t][nt][0], acc);
                acc = mfma_bf16(a[1], wf[t][nt][1], acc);
#pragma unroll
                for (int reg = 0; reg < 4; ++reg) {
                    int r = rbase + g * 4 + reg;        // (n,l,h) flat
                    int n = r >> 14, l = (r >> 3) & (LL - 1), h = r & 7;
                    int o = nt * 16 + c;
                    float vv = acc[reg];
                    if (t == 2) {
                        Qp[(((n * HH + h) * LL) + l) * DD + o] =
                            f2bf(vv * 0.04419417382415922f);   // 1/sqrt(512)
                    } else if (t == 1) {
                        Kp[(((n * HH + h) * LL) + l) * DD + o] = f2bf(vv);
                    } else {
                        VpT[((n * HH + h) * DD + o) * LL + l] = f2bf(vv);
                    }
                }
            }
        }
    }
}

// ---------------------------------------------------------------- K2: causal flash attention
// grid (L/64, N*H). block = 256 (4 waves x 16 q-rows). KV tiles of 32.
__global__ __launch_bounds__(256) void k_attn(const unsigned short* __restrict__ Qp,
                                              const unsigned short* __restrict__ Kp,
                                              const unsigned short* __restrict__ VpT,
                                              unsigned short* __restrict__ Xattn) {
    __shared__ __align__(16) unsigned short Kt[32 * 64];     // swizzled, 128B rows
    __shared__ __align__(16) unsigned short Vt[64 * 56];     // [d][kv], 112B row stride (pad)
    __shared__ __align__(16) unsigned short Pt[4][16 * 32];  // per wave, 64B rows, swizzled

    const int tid = threadIdx.x;
    const int w = tid >> 6, ln = tid & 63, c = ln & 15, g = ln >> 4;
    const int qbase = blockIdx.x * 64;
    const int nh = blockIdx.y;

    const unsigned short* Qb = Qp + (size_t)nh * (LL * DD);
    const unsigned short* Kb = Kp + (size_t)nh * (LL * DD);
    const unsigned short* Vb = VpT + (size_t)nh * (LL * DD);

    // Q fragments (A-layout: row = lane&15, k = (lane>>4)*8+j), scale already applied
    short8 qf[2];
    for (int kk = 0; kk < 2; ++kk)
        qf[kk] = *(const short8*)(Qb + (qbase + w * 16 + c) * DD + kk * 32 + g * 8);

    f32x4 oacc[4] = {};
    float m[4], lsum[4];
#pragma unroll
    for (int r = 0; r < 4; ++r) { m[r] = -1e30f; lsum[r] = 0.f; }

    const int ntile = qbase / 32 + 2;
    const int wrow0 = qbase + w * 16;

    for (int t = 0; t < ntile; ++t) {
        const int kb = t * 32;
        __syncthreads();   // protect LDS against previous iteration readers
        {   // stage K tile [32][64] bf16, contiguous 4KB, XOR swizzle on 128B rows
            const uint4* src = (const uint4*)(Kb + kb * DD);
            int row = tid >> 3, col8 = tid & 7;
            unsigned off = (unsigned)(row * 128 + col8 * 16) ^ (unsigned)((row & 7) << 4);
            *(uint4*)((char*)Kt + off) = src[tid];
        }
        {   // stage V^T tile [64][32] bf16 into 112B-stride rows
            int d = tid >> 2, seg = tid & 3;
            const uint4* src = (const uint4*)(Vb + d * LL + kb + seg * 8);
            *(uint4*)((char*)Vt + d * 112 + seg * 16) = *src;
        }
        __syncthreads();

        // QK^T: two 16x16 score tiles (cols kb+hf*16+c)
        f32x4 s[2];
        for (int hf = 0; hf < 2; ++hf) {
            f32x4 acc = {0.f, 0.f, 0.f, 0.f};
#pragma unroll
            for (int kk = 0; kk < 2; ++kk) {
                int colr = hf * 16 + c;
                unsigned off = (unsigned)(colr * 128 + kk * 64 + g * 16) ^
                               (unsigned)((colr & 7) << 4);
                short8 kf = *(const short8*)((char*)Kt + off);
                acc = mfma_bf16(qf[kk], kf, acc);
            }
            s[hf] = acc;
        }

        // causal mask (wave-uniform skip when whole tile is past)
        if (kb + 31 > wrow0) {
#pragma unroll
            for (int hf = 0; hf < 2; ++hf)
#pragma unroll
                for (int reg = 0; reg < 4; ++reg) {
                    int col = kb + hf * 16 + c;
                    int rowq = wrow0 + g * 4 + reg;
                    if (col > rowq) s[hf][reg] = -1e30f;
                }
        }

        // online softmax (per q-row state replicated across the 16 lanes of each g-group)
        float f[4];
#pragma unroll
        for (int reg = 0; reg < 4; ++reg) {
            float rm = fmaxf(s[0][reg], s[1][reg]);
            for (int off = 1; off < 16; off <<= 1) rm = fmaxf(rm, __shfl_xor(rm, off, 64));
            float mn = fmaxf(m[reg], rm);
            f[reg] = __expf(m[reg] - mn);
            m[reg] = mn;
            float p0 = __expf(s[0][reg] - mn);
            float p1 = __expf(s[1][reg] - mn);
            s[0][reg] = p0;
            s[1][reg] = p1;
            float rs = p0 + p1;
            for (int off = 1; off < 16; off <<= 1) rs += __shfl_xor(rs, off, 64);
            lsum[reg] = lsum[reg] * f[reg] + rs;
        }

        // P -> bf16 A-fragment layout via per-wave LDS transpose (swizzled 64B rows)
        unsigned short* pw = Pt[w];
#pragma unroll
        for (int hf = 0; hf < 2; ++hf)
#pragma unroll
            for (int reg = 0; reg < 4; ++reg) {
                int rowp = g * 4 + reg, colp = hf * 16 + c;
                unsigned off = (unsigned)(rowp * 64 + colp * 2) ^
                               (unsigned)(((rowp >> 2) & 3) << 4);
                *(unsigned short*)((char*)pw + off) = f2bf(s[hf][reg]);
            }

        // rescale O accumulators
#pragma unroll
        for (int dt = 0; dt < 4; ++dt)
#pragma unroll
            for (int reg = 0; reg < 4; ++reg) oacc[dt][reg] *= f[reg];

        // read P fragment (same-wave DS ops are in-order; may-alias keeps compiler honest)
        unsigned offp = (unsigned)(c * 64 + ((g ^ ((c >> 2) & 3)) << 4));
        short8 pf = *(const short8*)((char*)pw + offp);

        // PV: B[k=kv][col=d] = V^T[d][kv] rows from LDS
#pragma unroll
        for (int dt = 0; dt < 4; ++dt) {
            short8 vf = *(const short8*)((char*)Vt + (dt * 16 + c) * 112 + g * 16);
            oacc[dt] = mfma_bf16(pf, vf, oacc[dt]);
        }
    }

    // epilogue: normalize, store bf16 [n, l, h*64+d]
    int n = nh >> 3, h = nh & 7;
#pragma unroll
    for (int reg = 0; reg < 4; ++reg) {
        int rowq = qbase + w * 16 + g * 4 + reg;
        float inv = 1.0f / lsum[reg];
#pragma unroll
        for (int dt = 0; dt < 4; ++dt) {
            Xattn[((size_t)(n * LL + rowq)) * EE + h * DD + dt * 16 + c] =
                f2bf(oacc[dt][reg] * inv);
        }
    }
}

// ---------------------------------------------------------------- K3: out = X @ Wo^T + bo (fp32)
// grid (8192/64, 512/64). block 256 = 4 waves, each wave 16(M)x64(N).
__global__ __launch_bounds__(256) void k_out(const unsigned short* __restrict__ X,
                                             const unsigned short* __restrict__ Wob,
                                             const float* __restrict__ bo,
                                             float* __restrict__ out) {
    const int tid = threadIdx.x, w = tid >> 6, ln = tid & 63, c = ln & 15, g = ln >> 4;
    const int mbase = blockIdx.x * 64 + w * 16;
    const int nbase = blockIdx.y * 64;

    f32x4 acc[4] = {};
    for (int ks = 0; ks < 16; ++ks) {
        short8 a = *(const short8*)(X + (size_t)(mbase + c) * EE + ks * 32 + g * 8);
#pragma unroll
        for (int nt = 0; nt < 4; ++nt) {
            short8 b = *(const short8*)(Wob + (size_t)(nbase + nt * 16 + c) * EE + ks * 32 + g * 8);
            acc[nt] = mfma_bf16(a, b, acc[nt]);
        }
    }
#pragma unroll
    for (int nt = 0; nt < 4; ++nt) {
        float bias = bo[nbase + nt * 16 + c];
#pragma unroll
        for (int reg = 0; reg < 4; ++reg) {
            int row = mbase + g * 4 + reg;
            out[(size_t)row * EE + nbase + nt * 16 + c] = acc[nt][reg] + bias;
        }
    }
}

// ---------------------------------------------------------------- launch
extern "C" void kernel_launch(void* const* d_in, const int* in_sizes, int n_in,
                              void* d_out, int out_size, void* d_ws, size_t ws_size,
                              hipStream_t stream) {
    const float* vals = (const float*)d_in[0];
    const float* keys = (const float*)d_in[1];
    const float* qry  = (const float*)d_in[2];
    // d_in[3] = causal mask: constant tril, implemented analytically in k_attn
    const float* Wv = (const float*)d_in[4];
    const float* Wk = (const float*)d_in[5];
    const float* Wq = (const float*)d_in[6];
    const float* Wo = (const float*)d_in[7];
    const float* bo = (const float*)d_in[8];
    float* out = (float*)d_out;

    char* ws = (char*)d_ws;
    unsigned short* Qp  = (unsigned short*)(ws);                  // 8 MB  [n,h,l,d]
    unsigned short* Kp  = (unsigned short*)(ws + (8u  << 20));    // 8 MB  [n,h,l,d]
    unsigned short* VpT = (unsigned short*)(ws + (16u << 20));    // 8 MB  [n,h,d,l]
    unsigned short* Xa  = (unsigned short*)(ws + (24u << 20));    // 8 MB  [n,l,e]
    unsigned short* Wob = (unsigned short*)(ws + (32u << 20));    // 0.5 MB

    hipLaunchKernelGGL(k_cvt, dim3(256), dim3(256), 0, stream, Wo, Wob, EE * EE);
    hipLaunchKernelGGL(k_proj, dim3(256), dim3(256), 0, stream,
                       vals, keys, qry, Wv, Wk, Wq, Qp, Kp, VpT);
    hipLaunchKernelGGL(k_attn, dim3(LL / 64, NB * HH), dim3(256), 0, stream,
                       Qp, Kp, VpT, Xa);
    hipLaunchKernelGGL(k_out, dim3((NB * LL) / 64, EE / 64), dim3(256), 0, stream,
                       Xa, Wob, bo, out);
}

// Round 2
// 142.178 us; speedup vs baseline: 1.6205x; 1.6205x over previous
//
#include <hip/hip_runtime.h>

// Problem constants
#define NB 4
#define LL 2048
#define EE 512
#define HH 8
#define DD 64

typedef __attribute__((ext_vector_type(8))) short short8;
typedef __attribute__((ext_vector_type(4))) float f32x4;
typedef __attribute__((ext_vector_type(16))) float f32x16;
typedef __attribute__((ext_vector_type(4))) unsigned int u32x4;
typedef __bf16 bf16x8 __attribute__((ext_vector_type(8)));

static __device__ __forceinline__ unsigned short f2bf(float f) {
    unsigned u = __builtin_bit_cast(unsigned, f);
    unsigned r = u + 0x7FFFu + ((u >> 16) & 1u);   // RNE
    return (unsigned short)(r >> 16);
}

static __device__ __forceinline__ unsigned pkbf(float lo, float hi) {
    unsigned short a = __builtin_bit_cast(unsigned short, (__bf16)lo);
    unsigned short b = __builtin_bit_cast(unsigned short, (__bf16)hi);
    return (unsigned)a | ((unsigned)b << 16);
}

static __device__ __forceinline__ f32x4 mfma16(short8 a, short8 b, f32x4 c) {
    return __builtin_amdgcn_mfma_f32_16x16x32_bf16(
        __builtin_bit_cast(bf16x8, a), __builtin_bit_cast(bf16x8, b), c, 0, 0, 0);
}

static __device__ __forceinline__ f32x16 mfma32(short8 a, short8 b, f32x16 c) {
    return __builtin_amdgcn_mfma_f32_32x32x16_bf16(
        __builtin_bit_cast(bf16x8, a), __builtin_bit_cast(bf16x8, b), c, 0, 0, 0);
}

// ---------------------------------------------------------------- K0: Wo -> bf16
__global__ __launch_bounds__(256) void k_cvt(const float* __restrict__ src,
                                             unsigned short* __restrict__ dst, int n) {
    int i = (blockIdx.x * 256 + threadIdx.x) * 4;
    if (i < n) {
        float4 v = *(const float4*)(src + i);
        dst[i + 0] = f2bf(v.x);
        dst[i + 1] = f2bf(v.y);
        dst[i + 2] = f2bf(v.z);
        dst[i + 3] = f2bf(v.w);
    }
}

// ---------------------------------------------------------------- K1: QKV projections
// rows = (n,l,h) flat = 65536, each row 64 fp32. All outputs [n,h,l,d] bf16, coalesced.
// Q pre-scaled by 1/sqrt(512).
__global__ __launch_bounds__(256) void k_proj(const float* __restrict__ vals,
                                              const float* __restrict__ keys,
                                              const float* __restrict__ qry,
                                              const float* __restrict__ Wv,
                                              const float* __restrict__ Wk,
                                              const float* __restrict__ Wq,
                                              unsigned short* __restrict__ Qp,
                                              unsigned short* __restrict__ Kp,
                                              unsigned short* __restrict__ Vp) {
    const int tid = threadIdx.x;
    const int w = tid >> 6, ln = tid & 63;
    const int c = ln & 15, g = ln >> 4;

    const float* Ws[3] = {Wv, Wk, Wq};
    short8 wf[3][4][2];
    for (int t = 0; t < 3; ++t)
        for (int nt = 0; nt < 4; ++nt)
            for (int kk = 0; kk < 2; ++kk) {
                const float* p = Ws[t] + (nt * 16 + c) * DD + kk * 32 + g * 8;
                short8 v;
#pragma unroll
                for (int j = 0; j < 8; ++j) v[j] = (short)f2bf(p[j]);
                wf[t][nt][kk] = v;
            }

    const float* Xs[3] = {vals, keys, qry};
    for (int rt = 0; rt < 4; ++rt) {
        const int rbase = blockIdx.x * 256 + rt * 64 + w * 16;
        for (int t = 0; t < 3; ++t) {
            short8 a[2];
            for (int kk = 0; kk < 2; ++kk) {
                const float* p = Xs[t] + (rbase + c) * DD + kk * 32 + g * 8;
                short8 v;
#pragma unroll
                for (int j = 0; j < 8; ++j) v[j] = (short)f2bf(p[j]);
                a[kk] = v;
            }
            for (int nt = 0; nt < 4; ++nt) {
                f32x4 acc = {0.f, 0.f, 0.f, 0.f};
                acc = mfma16(a[0], wf[t][nt][0], acc);
                acc = mfma16(a[1], wf[t][nt][1], acc);
#pragma unroll
                for (int reg = 0; reg < 4; ++reg) {
                    int r = rbase + g * 4 + reg;        // (n,l,h) flat
                    int n = r >> 14, l = (r >> 3) & (LL - 1), h = r & 7;
                    int o = nt * 16 + c;
                    size_t idx = (((size_t)(n * HH + h) * LL) + l) * DD + o;
                    float vv = acc[reg];
                    if (t == 2)      Qp[idx] = f2bf(vv * 0.04419417382415922f);
                    else if (t == 1) Kp[idx] = f2bf(vv);
                    else             Vp[idx] = f2bf(vv);
                }
            }
        }
    }
}

// ---------------------------------------------------------------- K2 helpers
static __device__ __forceinline__ void k_issue(const unsigned short* Kb, int tt,
                                               unsigned short* Kbuf, int w, int ln) {
    const unsigned short* ksrc = Kb + (size_t)tt * (64 * DD);
#pragma unroll
    for (int r = 0; r < 2; ++r) {
        int qi = w * 2 + r;
        int row = qi * 8 + (ln >> 3);
        int s = (ln & 7) ^ (row & 7);
        __builtin_amdgcn_global_load_lds(
            (const __attribute__((address_space(1))) unsigned int*)(ksrc + row * 64 + s * 8),
            (__attribute__((address_space(3))) unsigned int*)(Kbuf + qi * 512),
            16, 0, 0);
    }
}

// ---------------------------------------------------------------- K2: causal flash attention
// grid: 512 blocks (balanced (i, nh) mapping), block = 256 = 4 waves.
// Wave w owns q-tile qt = 4*i + w (32 q rows). KV staged 64 at a time, double-buffered.
// S^T = K*Q^T via 32x32x16 MFMA (lane owns one q-row); softmax in-register;
// P exchanged lane<->lane+32; O^T = V^T * P^T.
__global__ __launch_bounds__(256) void k_attn(const unsigned short* __restrict__ Qp,
                                              const unsigned short* __restrict__ Kp,
                                              const unsigned short* __restrict__ Vp,
                                              unsigned short* __restrict__ Xa) {
    __shared__ __align__(16) unsigned short Kt[2][64 * 64];  // [kv][d], XOR swz ((row&7)<<4)
    __shared__ __align__(16) unsigned short Vt[2][64 * 64];  // [d][kv], XOR swz ((d&7)<<4)

    const int tid = threadIdx.x;
    const int w = tid >> 6, ln = tid & 63;
    const int c31 = ln & 31, g2 = ln >> 5;

    // balanced (i, nh): blocks b and b+256 sum to uniform work; heavy blocks first
    const int b = blockIdx.x;
    const int half = b >> 8, bb = b & 255, x = bb & 15;
    const int i = half ? x : 15 - x;
    const int nh = (bb >> 4) + 16 * half;
    const int qt = 4 * i + w;
    const int Q0 = qt * 32;
    const int nIter = 2 * i + 2;

    const unsigned short* Qb = Qp + (size_t)nh * (LL * DD);
    const unsigned short* Kb = Kp + (size_t)nh * (LL * DD);
    const unsigned short* Vb = Vp + (size_t)nh * (LL * DD);

    // Q fragments (B-operand: col=q=c31, k = kc*16 + 8*g2 + j)
    short8 qf[4];
#pragma unroll
    for (int kc = 0; kc < 4; ++kc)
        qf[kc] = *(const short8*)(Qb + (Q0 + c31) * DD + kc * 16 + g2 * 8);

    f32x16 oacc0, oacc1;
#pragma unroll
    for (int r = 0; r < 16; ++r) { oacc0[r] = 0.f; oacc1[r] = 0.f; }
    float m = -1e30f, l = 0.f;

    // V staging geometry: thread covers kv rows vkv0, vkv1 (16B of d each)
    const int vkv0 = (ln & 7) * 8 + w;
    const int vkv1 = vkv0 + 4;
    const int vds = ln >> 3;
    short8 vreg0, vreg1;

    // prologue: stage tile 0
    k_issue(Kb, 0, &Kt[0][0], w, ln);
    vreg0 = *(const short8*)(Vb + (size_t)0 + vkv0 * 64 + vds * 8);
    vreg1 = *(const short8*)(Vb + (size_t)0 + vkv1 * 64 + vds * 8);
    {
        char* vb_ = (char*)&Vt[0][0];
#pragma unroll
        for (int j = 0; j < 8; ++j) {
            int d = vds * 8 + j;
            *(unsigned short*)(vb_ + ((unsigned)(d * 128 + vkv0 * 2) ^ (unsigned)(j << 4))) =
                (unsigned short)vreg0[j];
            *(unsigned short*)(vb_ + ((unsigned)(d * 128 + vkv1 * 2) ^ (unsigned)(j << 4))) =
                (unsigned short)vreg1[j];
        }
    }
    __syncthreads();

    int cur = 0;
    for (int t = 0; t < nIter; ++t) {
        const int nxt = cur ^ 1;
        const bool pf = (t + 1 < nIter);
        if (pf) {   // issue next-tile loads before compute (latency hides under MFMA)
            k_issue(Kb, t + 1, &Kt[nxt][0], w, ln);
            const unsigned short* vsrc = Vb + (size_t)(t + 1) * (64 * DD);
            vreg0 = *(const short8*)(vsrc + vkv0 * 64 + vds * 8);
            vreg1 = *(const short8*)(vsrc + vkv1 * 64 + vds * 8);
        }

        const char* kb_ = (const char*)&Kt[cur][0];
        const char* vb_ = (const char*)&Vt[cur][0];

#pragma unroll
        for (int st = 0; st < 2; ++st) {
            const int kb32 = t * 64 + st * 32;
            if (kb32 <= Q0 + 31) {
                // ---- QK^T: S^T[kv][q], lane holds 16 kv values for q = Q0+c31
                f32x16 sc;
#pragma unroll
                for (int r = 0; r < 16; ++r) sc[r] = 0.f;
                {
                    const int R = st * 32 + c31;
                    const unsigned rb = (unsigned)(R * 128);
                    const unsigned swz = (unsigned)((R & 7) << 4);
                    short8 af0 = *(const short8*)(kb_ + rb + ((0u * 32 + g2 * 16) ^ swz));
                    short8 af1 = *(const short8*)(kb_ + rb + ((1u * 32 + g2 * 16) ^ swz));
                    short8 af2 = *(const short8*)(kb_ + rb + ((2u * 32 + g2 * 16) ^ swz));
                    short8 af3 = *(const short8*)(kb_ + rb + ((3u * 32 + g2 * 16) ^ swz));
                    sc = mfma32(af0, qf[0], sc);
                    sc = mfma32(af1, qf[1], sc);
                    sc = mfma32(af2, qf[2], sc);
                    sc = mfma32(af3, qf[3], sc);
                }
                const int q = Q0 + c31;
                if (kb32 + 31 > Q0) {   // diagonal tile: causal mask
#pragma unroll
                    for (int r = 0; r < 16; ++r) {
                        int kvg = kb32 + (r & 3) + 8 * (r >> 2) + 4 * g2;
                        sc[r] = (kvg > q) ? -1e30f : sc[r];
                    }
                }
                // ---- online softmax (state synced across the g2 pair)
                float tm = sc[0];
#pragma unroll
                for (int r = 1; r < 16; ++r) tm = fmaxf(tm, sc[r]);
                tm = fmaxf(tm, __shfl_xor(tm, 32));
                const float mn = fmaxf(m, tm);
                const float corr = __expf(m - mn);
                float ts = 0.f;
#pragma unroll
                for (int r = 0; r < 16; ++r) {
                    float p = __expf(sc[r] - mn);
                    sc[r] = p;
                    ts += p;
                }
                ts += __shfl_xor(ts, 32);
                l = l * corr + ts;
                m = mn;
#pragma unroll
                for (int r = 0; r < 16; ++r) { oacc0[r] *= corr; oacc1[r] *= corr; }

                // ---- pack P rows to bf16 pairs (quad a: kv = kb32 + 8a + 4g2 + 0..3)
                unsigned pk0 = pkbf(sc[0], sc[1]),   pk1 = pkbf(sc[2], sc[3]);
                unsigned pk2 = pkbf(sc[4], sc[5]),   pk3 = pkbf(sc[6], sc[7]);
                unsigned pk4 = pkbf(sc[8], sc[9]),   pk5 = pkbf(sc[10], sc[11]);
                unsigned pk6 = pkbf(sc[12], sc[13]), pk7 = pkbf(sc[14], sc[15]);

                // ---- PV: O^T += V^T * P^T over two 16-kv chunks
#pragma unroll
                for (int ck = 0; ck < 2; ++ck) {
                    unsigned a0 = ck ? pk4 : pk0, a1 = ck ? pk5 : pk1;   // quad 2ck
                    unsigned b0 = ck ? pk6 : pk2, b1 = ck ? pk7 : pk3;   // quad 2ck+1
                    unsigned xa0 = __shfl_xor(a0, 32);
                    unsigned xa1 = __shfl_xor(a1, 32);
                    unsigned xb0 = __shfl_xor(b0, 32);
                    unsigned xb1 = __shfl_xor(b1, 32);
                    u32x4 bfv;
                    bfv[0] = g2 ? xb0 : a0;
                    bfv[1] = g2 ? xb1 : a1;
                    bfv[2] = g2 ? b0 : xa0;
                    bfv[3] = g2 ? b1 : xa1;
                    short8 pB = __builtin_bit_cast(short8, bfv);
                    {
                        const int dP = c31;           // dt = 0
                        unsigned addr = (unsigned)(dP * 128) +
                            (((unsigned)(st * 64 + ck * 32 + g2 * 16)) ^ ((unsigned)((dP & 7) << 4)));
                        short8 A = *(const short8*)(vb_ + addr);
                        oacc0 = mfma32(A, pB, oacc0);
                    }
                    {
                        const int dP = 32 + c31;      // dt = 1
                        unsigned addr = (unsigned)(dP * 128) +
                            (((unsigned)(st * 64 + ck * 32 + g2 * 16)) ^ ((unsigned)((dP & 7) << 4)));
                        short8 A = *(const short8*)(vb_ + addr);
                        oacc1 = mfma32(A, pB, oacc1);
                    }
                }
            }
        }

        if (pf) {   // write next V^T tile (vmcnt auto-waited on vreg use)
            char* vb2 = (char*)&Vt[nxt][0];
#pragma unroll
            for (int j = 0; j < 8; ++j) {
                int d = vds * 8 + j;
                *(unsigned short*)(vb2 + ((unsigned)(d * 128 + vkv0 * 2) ^ (unsigned)(j << 4))) =
                    (unsigned short)vreg0[j];
                *(unsigned short*)(vb2 + ((unsigned)(d * 128 + vkv1 * 2) ^ (unsigned)(j << 4))) =
                    (unsigned short)vreg1[j];
            }
        }
        __syncthreads();
        cur = nxt;
    }

    // ---- epilogue: O = O^T normalized, store bf16 [n, l, h*64 + d]
    const float inv = 1.0f / l;
    const int n = nh >> 3, h = nh & 7;
    unsigned short* orow = Xa + ((size_t)(n * LL + Q0 + c31)) * EE + h * DD;
#pragma unroll
    for (int a = 0; a < 4; ++a) {
        {
            float e0 = oacc0[4 * a + 0] * inv, e1 = oacc0[4 * a + 1] * inv;
            float e2 = oacc0[4 * a + 2] * inv, e3 = oacc0[4 * a + 3] * inv;
            uint2 u = {pkbf(e0, e1), pkbf(e2, e3)};
            *(uint2*)(orow + a * 8 + g2 * 4) = u;
        }
        {
            float e0 = oacc1[4 * a + 0] * inv, e1 = oacc1[4 * a + 1] * inv;
            float e2 = oacc1[4 * a + 2] * inv, e3 = oacc1[4 * a + 3] * inv;
            uint2 u = {pkbf(e0, e1), pkbf(e2, e3)};
            *(uint2*)(orow + 32 + a * 8 + g2 * 4) = u;
        }
    }
}

// ---------------------------------------------------------------- K3: out = X @ Wo^T + bo (fp32)
__global__ __launch_bounds__(256) void k_out(const unsigned short* __restrict__ X,
                                             const unsigned short* __restrict__ Wob,
                                             const float* __restrict__ bo,
                                             float* __restrict__ out) {
    const int tid = threadIdx.x, w = tid >> 6, ln = tid & 63, c = ln & 15, g = ln >> 4;
    const int mbase = blockIdx.x * 64 + w * 16;
    const int nbase = blockIdx.y * 64;

    f32x4 acc[4] = {};
    for (int ks = 0; ks < 16; ++ks) {
        short8 a = *(const short8*)(X + (size_t)(mbase + c) * EE + ks * 32 + g * 8);
#pragma unroll
        for (int nt = 0; nt < 4; ++nt) {
            short8 bfr = *(const short8*)(Wob + (size_t)(nbase + nt * 16 + c) * EE + ks * 32 + g * 8);
            acc[nt] = mfma16(a, bfr, acc[nt]);
        }
    }
#pragma unroll
    for (int nt = 0; nt < 4; ++nt) {
        float bias = bo[nbase + nt * 16 + c];
#pragma unroll
        for (int reg = 0; reg < 4; ++reg) {
            int row = mbase + g * 4 + reg;
            out[(size_t)row * EE + nbase + nt * 16 + c] = acc[nt][reg] + bias;
        }
    }
}

// ---------------------------------------------------------------- launch
extern "C" void kernel_launch(void* const* d_in, const int* in_sizes, int n_in,
                              void* d_out, int out_size, void* d_ws, size_t ws_size,
                              hipStream_t stream) {
    const float* vals = (const float*)d_in[0];
    const float* keys = (const float*)d_in[1];
    const float* qry  = (const float*)d_in[2];
    // d_in[3] = causal mask (constant tril, analytic in k_attn)
    const float* Wv = (const float*)d_in[4];
    const float* Wk = (const float*)d_in[5];
    const float* Wq = (const float*)d_in[6];
    const float* Wo = (const float*)d_in[7];
    const float* bo = (const float*)d_in[8];
    float* out = (float*)d_out;

    char* ws = (char*)d_ws;
    unsigned short* Qp  = (unsigned short*)(ws);                  // 8 MB  [n,h,l,d]
    unsigned short* Kp  = (unsigned short*)(ws + (8u  << 20));    // 8 MB  [n,h,l,d]
    unsigned short* Vp  = (unsigned short*)(ws + (16u << 20));    // 8 MB  [n,h,l,d]
    unsigned short* Xa  = (unsigned short*)(ws + (24u << 20));    // 8 MB  [n,l,e]
    unsigned short* Wob = (unsigned short*)(ws + (32u << 20));    // 0.5 MB

    hipLaunchKernelGGL(k_cvt, dim3(256), dim3(256), 0, stream, Wo, Wob, EE * EE);
    hipLaunchKernelGGL(k_proj, dim3(256), dim3(256), 0, stream,
                       vals, keys, qry, Wv, Wk, Wq, Qp, Kp, Vp);
    hipLaunchKernelGGL(k_attn, dim3(512), dim3(256), 0, stream, Qp, Kp, Vp, Xa);
    hipLaunchKernelGGL(k_out, dim3((NB * LL) / 64, EE / 64), dim3(256), 0, stream,
                       Xa, Wob, bo, out);
}

// Round 3
// 134.396 us; speedup vs baseline: 1.7143x; 1.0579x over previous
//
#include <hip/hip_runtime.h>

// Problem constants
#define NB 4
#define LL 2048
#define EE 512
#define HH 8
#define DD 64

typedef __attribute__((ext_vector_type(8))) short short8;
typedef __attribute__((ext_vector_type(4))) float f32x4;
typedef __attribute__((ext_vector_type(16))) float f32x16;
typedef __attribute__((ext_vector_type(4))) unsigned int u32x4;
typedef __bf16 bf16x8 __attribute__((ext_vector_type(8)));

#if __has_builtin(__builtin_amdgcn_exp2f)
#define EXP2(x) __builtin_amdgcn_exp2f(x)
#else
#define EXP2(x) __expf((x) * 0.6931471805599453f)
#endif

static __device__ __forceinline__ short bfc(float f) {
    return __builtin_bit_cast(short, (__bf16)f);
}

static __device__ __forceinline__ unsigned pkbf(float lo, float hi) {
    unsigned short a = (unsigned short)(unsigned)__builtin_bit_cast(unsigned short, (__bf16)lo);
    unsigned short b = (unsigned short)(unsigned)__builtin_bit_cast(unsigned short, (__bf16)hi);
    return (unsigned)a | ((unsigned)b << 16);
}

static __device__ __forceinline__ f32x4 mfma16(short8 a, short8 b, f32x4 c) {
    return __builtin_amdgcn_mfma_f32_16x16x32_bf16(
        __builtin_bit_cast(bf16x8, a), __builtin_bit_cast(bf16x8, b), c, 0, 0, 0);
}

static __device__ __forceinline__ f32x16 mfma32(short8 a, short8 b, f32x16 c) {
    return __builtin_amdgcn_mfma_f32_32x32x16_bf16(
        __builtin_bit_cast(bf16x8, a), __builtin_bit_cast(bf16x8, b), c, 0, 0, 0);
}

// ---------------------------------------------------------------- K0: Wo -> bf16
__global__ __launch_bounds__(256) void k_cvt(const float* __restrict__ src,
                                             unsigned short* __restrict__ dst, int n) {
    int i = (blockIdx.x * 256 + threadIdx.x) * 4;
    if (i < n) {
        float4 v = *(const float4*)(src + i);
        dst[i + 0] = (unsigned short)bfc(v.x);
        dst[i + 1] = (unsigned short)bfc(v.y);
        dst[i + 2] = (unsigned short)bfc(v.z);
        dst[i + 3] = (unsigned short)bfc(v.w);
    }
}

// ---------------------------------------------------------------- K1: QKV projections
// rows = (n,l,h) flat = 65536, each row 64 fp32.
// Qp/Kp out [n,h,l,d] bf16 (Q pre-scaled by log2(e)/sqrt(512)); V out transposed [n,h,d,l].
__global__ __launch_bounds__(256) void k_proj(const float* __restrict__ vals,
                                              const float* __restrict__ keys,
                                              const float* __restrict__ qry,
                                              const float* __restrict__ Wv,
                                              const float* __restrict__ Wk,
                                              const float* __restrict__ Wq,
                                              unsigned short* __restrict__ Qp,
                                              unsigned short* __restrict__ Kp,
                                              unsigned short* __restrict__ VpT) {
    const int tid = threadIdx.x;
    const int w = tid >> 6, ln = tid & 63;
    const int c = ln & 15, g = ln >> 4;

    const float* Ws[3] = {Wv, Wk, Wq};
    short8 wf[3][4][2];
    for (int t = 0; t < 3; ++t)
        for (int nt = 0; nt < 4; ++nt)
            for (int kk = 0; kk < 2; ++kk) {
                const float* p = Ws[t] + (nt * 16 + c) * DD + kk * 32 + g * 8;
                short8 v;
#pragma unroll
                for (int j = 0; j < 8; ++j) v[j] = bfc(p[j]);
                wf[t][nt][kk] = v;
            }

    const float* Xs[3] = {vals, keys, qry};
    for (int rt = 0; rt < 4; ++rt) {
        const int rbase = blockIdx.x * 256 + rt * 64 + w * 16;
        for (int t = 0; t < 3; ++t) {
            short8 a[2];
            for (int kk = 0; kk < 2; ++kk) {
                const float* p = Xs[t] + (rbase + c) * DD + kk * 32 + g * 8;
                short8 v;
#pragma unroll
                for (int j = 0; j < 8; ++j) v[j] = bfc(p[j]);
                a[kk] = v;
            }
            for (int nt = 0; nt < 4; ++nt) {
                f32x4 acc = {0.f, 0.f, 0.f, 0.f};
                acc = mfma16(a[0], wf[t][nt][0], acc);
                acc = mfma16(a[1], wf[t][nt][1], acc);
#pragma unroll
                for (int reg = 0; reg < 4; ++reg) {
                    int r = rbase + g * 4 + reg;        // (n,l,h) flat
                    int n = r >> 14, l = (r >> 3) & (LL - 1), h = r & 7;
                    int o = nt * 16 + c;
                    int nh = n * HH + h;
                    float vv = acc[reg];
                    if (t == 2) {
                        // scale = log2(e)/sqrt(512)
                        Qp[((size_t)nh * LL + l) * DD + o] =
                            (unsigned short)bfc(vv * (0.04419417382415922f * 1.4426950408889634f));
                    } else if (t == 1) {
                        Kp[((size_t)nh * LL + l) * DD + o] = (unsigned short)bfc(vv);
                    } else {
                        VpT[((size_t)nh * DD + o) * LL + l] = (unsigned short)bfc(vv);
                    }
                }
            }
        }
    }
}

// ---------------------------------------------------------------- K2 staging helper
// Stage a 64x64 bf16 tile (row-major, row stride rstride elems) into LDS via
// global_load_lds, with the XOR bank swizzle ((row&7) on 16B chunks) folded
// into the per-lane global source address. LDS dest is linear.
static __device__ __forceinline__ void stage_tile(const unsigned short* __restrict__ src,
                                                  unsigned short* buf, int w, int ln,
                                                  size_t rstride) {
#pragma unroll
    for (int r = 0; r < 2; ++r) {
        int qi = w * 2 + r;
        int row = qi * 8 + (ln >> 3);
        int s = (ln & 7) ^ (row & 7);
        __builtin_amdgcn_global_load_lds(
            (const __attribute__((address_space(1))) unsigned int*)(src + (size_t)row * rstride + s * 8),
            (__attribute__((address_space(3))) unsigned int*)(buf + qi * 512),
            16, 0, 0);
    }
}

// ---------------------------------------------------------------- K2: causal flash attention
// grid: 512 blocks (balanced (i, nh) mapping), block = 256 = 4 waves.
// Wave w owns q-tile qt = 4*i + w (32 q rows). KV staged 64 at a time, double-buffered.
// S^T = K*Q^T via 32x32x16 MFMA (lane owns one q-row); one softmax round per 64 kv
// (exp2 domain, defer-max); P exchanged lane<->lane+32; O^T = V^T * P^T.
__global__ __launch_bounds__(256) void k_attn(const unsigned short* __restrict__ Qp,
                                              const unsigned short* __restrict__ Kp,
                                              const unsigned short* __restrict__ VpT,
                                              unsigned short* __restrict__ Xa) {
    __shared__ __align__(16) unsigned short Kt[2][64 * 64];  // [kv][d], swz ((kv&7)<<4)
    __shared__ __align__(16) unsigned short Vt[2][64 * 64];  // [d][kv], swz ((d&7)<<4)

    const int tid = threadIdx.x;
    const int w = tid >> 6, ln = tid & 63;
    const int c31 = ln & 31, g2 = ln >> 5;

    // balanced (i, nh): blocks b and b+256 sum to uniform work; heavy blocks first
    const int b = blockIdx.x;
    const int half = b >> 8, bb = b & 255, x = bb & 15;
    const int i = half ? x : 15 - x;
    const int nh = (bb >> 4) + 16 * half;
    const int qt = 4 * i + w;
    const int Q0 = qt * 32;
    const int nIter = 2 * i + 2;

    const unsigned short* Qb = Qp + (size_t)nh * (LL * DD);
    const unsigned short* Kb = Kp + (size_t)nh * (LL * DD);
    const unsigned short* VbT = VpT + (size_t)nh * (LL * DD);

    // Q fragments (B-operand: col=q=c31, k = kc*16 + 8*g2 + j)
    short8 qf[4];
#pragma unroll
    for (int kc = 0; kc < 4; ++kc)
        qf[kc] = *(const short8*)(Qb + (Q0 + c31) * DD + kc * 16 + g2 * 8);

    f32x16 oacc0, oacc1;
#pragma unroll
    for (int r = 0; r < 16; ++r) { oacc0[r] = 0.f; oacc1[r] = 0.f; }
    float m = -1e30f, lsum = 0.f;

    // prologue: stage tile 0
    stage_tile(Kb, &Kt[0][0], w, ln, DD);
    stage_tile(VbT, &Vt[0][0], w, ln, LL);
    __syncthreads();

    int cur = 0;
    for (int t = 0; t < nIter; ++t) {
        const int nxt = cur ^ 1;
        if (t + 1 < nIter) {   // prefetch next tile (drained by the end-of-iter barrier)
            stage_tile(Kb + (size_t)(t + 1) * (64 * DD), &Kt[nxt][0], w, ln, DD);
            stage_tile(VbT + (size_t)(t + 1) * 64, &Vt[nxt][0], w, ln, LL);
        }

        if (t * 64 <= Q0 + 31) {    // wave-active tile
            const char* kb_ = (const char*)&Kt[cur][0];
            const char* vb_ = (const char*)&Vt[cur][0];
            const bool act1 = (t * 64 + 32 <= Q0 + 31);
            const int q = Q0 + c31;

            // ---- QK^T: S^T[kv][q] for 64 kv (lane owns q-row = c31)
            f32x16 sc0, sc1;
#pragma unroll
            for (int r = 0; r < 16; ++r) { sc0[r] = 0.f; sc1[r] = 0.f; }
            {
                const int R = c31;
                const unsigned rb = (unsigned)(R * 128);
                const unsigned swz = (unsigned)((R & 7) << 4);
#pragma unroll
                for (int kc = 0; kc < 4; ++kc) {
                    short8 af = *(const short8*)(kb_ + rb + (((unsigned)(kc * 32 + g2 * 16)) ^ swz));
                    sc0 = mfma32(af, qf[kc], sc0);
                }
            }
            if (act1) {
                const int R = 32 + c31;
                const unsigned rb = (unsigned)(R * 128);
                const unsigned swz = (unsigned)((R & 7) << 4);
#pragma unroll
                for (int kc = 0; kc < 4; ++kc) {
                    short8 af = *(const short8*)(kb_ + rb + (((unsigned)(kc * 32 + g2 * 16)) ^ swz));
                    sc1 = mfma32(af, qf[kc], sc1);
                }
            }

            // ---- causal mask on the diagonal subtiles
            if (t * 64 + 31 > Q0) {
#pragma unroll
                for (int r = 0; r < 16; ++r) {
                    int kvg = t * 64 + (r & 3) + 8 * (r >> 2) + 4 * g2;
                    sc0[r] = (kvg > q) ? -1e30f : sc0[r];
                }
            }
            if (act1 && t * 64 + 63 > Q0) {
#pragma unroll
                for (int r = 0; r < 16; ++r) {
                    int kvg = t * 64 + 32 + (r & 3) + 8 * (r >> 2) + 4 * g2;
                    sc1[r] = (kvg > q) ? -1e30f : sc1[r];
                }
            }

            // ---- one online-softmax round over up to 64 kv (exp2 domain)
            float tm;
            {
                float a[8];
#pragma unroll
                for (int r = 0; r < 8; ++r) a[r] = fmaxf(sc0[r], sc0[r + 8]);
                if (act1) {
#pragma unroll
                    for (int r = 0; r < 8; ++r)
                        a[r] = fmaxf(a[r], fmaxf(sc1[r], sc1[r + 8]));
                }
                float b0 = fmaxf(a[0], a[4]), b1 = fmaxf(a[1], a[5]);
                float b2 = fmaxf(a[2], a[6]), b3 = fmaxf(a[3], a[7]);
                tm = fmaxf(fmaxf(b0, b1), fmaxf(b2, b3));
            }
            tm = fmaxf(tm, __shfl_xor(tm, 32));

            // defer-max: only rescale when the running max grew by > 6 (log2 units)
            if (!__all(tm <= m + 6.0f)) {
                float mn = fmaxf(m, tm);
                float corr = EXP2(m - mn);
                m = mn;
                lsum *= corr;
#pragma unroll
                for (int r = 0; r < 16; ++r) { oacc0[r] *= corr; oacc1[r] *= corr; }
            }

#pragma unroll
            for (int r = 0; r < 16; ++r) sc0[r] = EXP2(sc0[r] - m);
            if (act1) {
#pragma unroll
                for (int r = 0; r < 16; ++r) sc1[r] = EXP2(sc1[r] - m);
            }
            {
                float a[8];
#pragma unroll
                for (int r = 0; r < 8; ++r) a[r] = sc0[r] + sc0[r + 8];
                if (act1) {
#pragma unroll
                    for (int r = 0; r < 8; ++r) a[r] += sc1[r] + sc1[r + 8];
                }
                float b0 = a[0] + a[4], b1 = a[1] + a[5];
                float b2 = a[2] + a[6], b3 = a[3] + a[7];
                float ts = (b0 + b1) + (b2 + b3);
                ts += __shfl_xor(ts, 32);
                lsum += ts;
            }

            // ---- PV per 32-kv subtile: pack P to bf16, exchange halves, 4 MFMA
#pragma unroll
            for (int st = 0; st < 2; ++st) {
                if (st == 1 && !act1) break;
                const f32x16& sc = st ? sc1 : sc0;
                unsigned pk[8];
#pragma unroll
                for (int iw = 0; iw < 8; ++iw) pk[iw] = pkbf(sc[2 * iw], sc[2 * iw + 1]);
#pragma unroll
                for (int ck = 0; ck < 2; ++ck) {
                    unsigned s0 = g2 ? pk[4 * ck + 0] : pk[4 * ck + 2];
                    unsigned s1 = g2 ? pk[4 * ck + 1] : pk[4 * ck + 3];
                    unsigned x0 = __shfl_xor(s0, 32);
                    unsigned x1 = __shfl_xor(s1, 32);
                    u32x4 bfv;
                    bfv[0] = g2 ? x0 : pk[4 * ck + 0];
                    bfv[1] = g2 ? x1 : pk[4 * ck + 1];
                    bfv[2] = g2 ? pk[4 * ck + 2] : x0;
                    bfv[3] = g2 ? pk[4 * ck + 3] : x1;
                    short8 pB = __builtin_bit_cast(short8, bfv);
                    const unsigned coff = (unsigned)(st * 64 + ck * 32 + g2 * 16);
                    {
                        const int dP = c31;
                        short8 A = *(const short8*)(vb_ + (unsigned)(dP * 128) +
                                                    (coff ^ ((unsigned)((dP & 7) << 4))));
                        oacc0 = mfma32(A, pB, oacc0);
                    }
                    {
                        const int dP = 32 + c31;
                        short8 A = *(const short8*)(vb_ + (unsigned)(dP * 128) +
                                                    (coff ^ ((unsigned)((dP & 7) << 4))));
                        oacc1 = mfma32(A, pB, oacc1);
                    }
                }
            }
        }

        __syncthreads();
        cur = nxt;
    }

    // ---- epilogue: O = O^T normalized, store bf16 [n, l, h*64 + d]
    const float inv = 1.0f / lsum;
    const int n = nh >> 3, h = nh & 7;
    unsigned short* orow = Xa + ((size_t)(n * LL + Q0 + c31)) * EE + h * DD;
#pragma unroll
    for (int a = 0; a < 4; ++a) {
        {
            float e0 = oacc0[4 * a + 0] * inv, e1 = oacc0[4 * a + 1] * inv;
            float e2 = oacc0[4 * a + 2] * inv, e3 = oacc0[4 * a + 3] * inv;
            uint2 u = {pkbf(e0, e1), pkbf(e2, e3)};
            *(uint2*)(orow + a * 8 + g2 * 4) = u;
        }
        {
            float e0 = oacc1[4 * a + 0] * inv, e1 = oacc1[4 * a + 1] * inv;
            float e2 = oacc1[4 * a + 2] * inv, e3 = oacc1[4 * a + 3] * inv;
            uint2 u = {pkbf(e0, e1), pkbf(e2, e3)};
            *(uint2*)(orow + 32 + a * 8 + g2 * 4) = u;
        }
    }
}

// ---------------------------------------------------------------- K3: out = X @ Wo^T + bo (fp32)
__global__ __launch_bounds__(256) void k_out(const unsigned short* __restrict__ X,
                                             const unsigned short* __restrict__ Wob,
                                             const float* __restrict__ bo,
                                             float* __restrict__ out) {
    const int tid = threadIdx.x, w = tid >> 6, ln = tid & 63, c = ln & 15, g = ln >> 4;
    const int mbase = blockIdx.x * 64 + w * 16;
    const int nbase = blockIdx.y * 64;

    f32x4 acc[4] = {};
    for (int ks = 0; ks < 16; ++ks) {
        short8 a = *(const short8*)(X + (size_t)(mbase + c) * EE + ks * 32 + g * 8);
#pragma unroll
        for (int nt = 0; nt < 4; ++nt) {
            short8 bfr = *(const short8*)(Wob + (size_t)(nbase + nt * 16 + c) * EE + ks * 32 + g * 8);
            acc[nt] = mfma16(a, bfr, acc[nt]);
        }
    }
#pragma unroll
    for (int nt = 0; nt < 4; ++nt) {
        float bias = bo[nbase + nt * 16 + c];
#pragma unroll
        for (int reg = 0; reg < 4; ++reg) {
            int row = mbase + g * 4 + reg;
            out[(size_t)row * EE + nbase + nt * 16 + c] = acc[nt][reg] + bias;
        }
    }
}

// ---------------------------------------------------------------- launch
extern "C" void kernel_launch(void* const* d_in, const int* in_sizes, int n_in,
                              void* d_out, int out_size, void* d_ws, size_t ws_size,
                              hipStream_t stream) {
    const float* vals = (const float*)d_in[0];
    const float* keys = (const float*)d_in[1];
    const float* qry  = (const float*)d_in[2];
    // d_in[3] = causal mask (constant tril, analytic in k_attn)
    const float* Wv = (const float*)d_in[4];
    const float* Wk = (const float*)d_in[5];
    const float* Wq = (const float*)d_in[6];
    const float* Wo = (const float*)d_in[7];
    const float* bo = (const float*)d_in[8];
    float* out = (float*)d_out;

    char* ws = (char*)d_ws;
    unsigned short* Qp  = (unsigned short*)(ws);                  // 8 MB  [n,h,l,d]
    unsigned short* Kp  = (unsigned short*)(ws + (8u  << 20));    // 8 MB  [n,h,l,d]
    unsigned short* VpT = (unsigned short*)(ws + (16u << 20));    // 8 MB  [n,h,d,l]
    unsigned short* Xa  = (unsigned short*)(ws + (24u << 20));    // 8 MB  [n,l,e]
    unsigned short* Wob = (unsigned short*)(ws + (32u << 20));    // 0.5 MB

    hipLaunchKernelGGL(k_cvt, dim3(256), dim3(256), 0, stream, Wo, Wob, EE * EE);
    hipLaunchKernelGGL(k_proj, dim3(256), dim3(256), 0, stream,
                       vals, keys, qry, Wv, Wk, Wq, Qp, Kp, VpT);
    hipLaunchKernelGGL(k_attn, dim3(512), dim3(256), 0, stream, Qp, Kp, VpT, Xa);
    hipLaunchKernelGGL(k_out, dim3((NB * LL) / 64, EE / 64), dim3(256), 0, stream,
                       Xa, Wob, bo, out);
}

// Round 4
// 113.820 us; speedup vs baseline: 2.0242x; 1.1808x over previous
//
#include <hip/hip_runtime.h>

// Problem constants
#define NB 4
#define LL 2048
#define EE 512
#define HH 8
#define DD 64

typedef __attribute__((ext_vector_type(8))) short short8;
typedef __attribute__((ext_vector_type(4))) float f32x4;
typedef __attribute__((ext_vector_type(16))) float f32x16;
typedef __attribute__((ext_vector_type(4))) unsigned int u32x4;
typedef __bf16 bf16x8 __attribute__((ext_vector_type(8)));

#if __has_builtin(__builtin_amdgcn_exp2f)
#define EXP2(x) __builtin_amdgcn_exp2f(x)
#else
#define EXP2(x) __expf((x) * 0.6931471805599453f)
#endif

static __device__ __forceinline__ short bfc(float f) {
    return __builtin_bit_cast(short, (__bf16)f);
}

static __device__ __forceinline__ unsigned pkbf(float lo, float hi) {
    unsigned short a = (unsigned short)(unsigned)__builtin_bit_cast(unsigned short, (__bf16)lo);
    unsigned short b = (unsigned short)(unsigned)__builtin_bit_cast(unsigned short, (__bf16)hi);
    return (unsigned)a | ((unsigned)b << 16);
}

static __device__ __forceinline__ f32x4 mfma16(short8 a, short8 b, f32x4 c) {
    return __builtin_amdgcn_mfma_f32_16x16x32_bf16(
        __builtin_bit_cast(bf16x8, a), __builtin_bit_cast(bf16x8, b), c, 0, 0, 0);
}

static __device__ __forceinline__ f32x16 mfma32(short8 a, short8 b, f32x16 c) {
    return __builtin_amdgcn_mfma_f32_32x32x16_bf16(
        __builtin_bit_cast(bf16x8, a), __builtin_bit_cast(bf16x8, b), c, 0, 0, 0);
}

// ---------------------------------------------------------------- K0: Wo -> bf16
__global__ __launch_bounds__(256) void k_cvt(const float* __restrict__ src,
                                             unsigned short* __restrict__ dst, int n) {
    int i = (blockIdx.x * 256 + threadIdx.x) * 4;
    if (i < n) {
        float4 v = *(const float4*)(src + i);
        dst[i + 0] = (unsigned short)bfc(v.x);
        dst[i + 1] = (unsigned short)bfc(v.y);
        dst[i + 2] = (unsigned short)bfc(v.z);
        dst[i + 3] = (unsigned short)bfc(v.w);
    }
}

// ---------------------------------------------------------------- K1: QKV projections
// Block: 512 threads (8 waves), 256 consecutive (n,l,h)-rows (n fixed, 32 l x 8 h).
// Qp/Kp out [n,h,l,d] bf16 (Q pre-scaled by log2(e)/sqrt(512)).
// V out TILED [nh][l>>6][d][l&63] via LDS transpose -> coalesced 64B stores.
__global__ __launch_bounds__(512) void k_proj(const float* __restrict__ vals,
                                              const float* __restrict__ keys,
                                              const float* __restrict__ qry,
                                              const float* __restrict__ Wv,
                                              const float* __restrict__ Wk,
                                              const float* __restrict__ Wq,
                                              unsigned short* __restrict__ Qp,
                                              unsigned short* __restrict__ Kp,
                                              unsigned short* __restrict__ Vg) {
    __shared__ __align__(16) unsigned short vt[8 * 64 * 40];  // [h][d][pad 40]

    const int tid = threadIdx.x;
    const int w = tid >> 6, ln = tid & 63;
    const int c = ln & 15, g = ln >> 4;
    const int r0 = blockIdx.x * 256;
    const int n = r0 >> 14;
    const int l0 = (r0 >> 3) & (LL - 1);

    // ---- phase A: V projection -> LDS transpose tile
    {
        short8 wf[4][2];
#pragma unroll
        for (int nt = 0; nt < 4; ++nt)
#pragma unroll
            for (int kk = 0; kk < 2; ++kk) {
                const float* p = Wv + (nt * 16 + c) * DD + kk * 32 + g * 8;
                short8 v;
#pragma unroll
                for (int j = 0; j < 8; ++j) v[j] = bfc(p[j]);
                wf[nt][kk] = v;
            }
        for (int rt = 0; rt < 2; ++rt) {
            const int rbase = r0 + rt * 128 + w * 16;
            short8 a[2];
#pragma unroll
            for (int kk = 0; kk < 2; ++kk) {
                const float* p = vals + (size_t)(rbase + c) * DD + kk * 32 + g * 8;
                short8 v;
#pragma unroll
                for (int j = 0; j < 8; ++j) v[j] = bfc(p[j]);
                a[kk] = v;
            }
#pragma unroll
            for (int nt = 0; nt < 4; ++nt) {
                f32x4 acc = {0.f, 0.f, 0.f, 0.f};
                acc = mfma16(a[0], wf[nt][0], acc);
                acc = mfma16(a[1], wf[nt][1], acc);
#pragma unroll
                for (int reg = 0; reg < 4; ++reg) {
                    int r = rbase + g * 4 + reg;
                    int h = r & 7, l31 = (r >> 3) & 31;
                    int o = nt * 16 + c;
                    vt[h * 2560 + o * 40 + l31] = (unsigned short)bfc(acc[reg]);
                }
            }
        }
    }
    __syncthreads();

    // ---- V writeout: 512 threads -> 512 (h,d) rows of 32 l = 64B contiguous
    {
        const int h = tid >> 6, d = tid & 63;
        const uint4* src = (const uint4*)(vt + h * 2560 + d * 40);
        unsigned short* dst = Vg + ((size_t)(n * HH + h) * (LL * DD)) +
                              (size_t)(l0 >> 6) * 4096 + d * 64 + (l0 & 63);
        uint4 v0 = src[0], v1 = src[1], v2 = src[2], v3 = src[3];
        *(uint4*)(dst + 0)  = v0;
        *(uint4*)(dst + 8)  = v1;
        *(uint4*)(dst + 16) = v2;
        *(uint4*)(dst + 24) = v3;
    }

    // ---- phase B: K and Q projections (direct coalesced-ish stores)
    {
        short8 wfk[4][2], wfq[4][2];
#pragma unroll
        for (int nt = 0; nt < 4; ++nt)
#pragma unroll
            for (int kk = 0; kk < 2; ++kk) {
                const float* pk = Wk + (nt * 16 + c) * DD + kk * 32 + g * 8;
                const float* pq = Wq + (nt * 16 + c) * DD + kk * 32 + g * 8;
                short8 vk, vq;
#pragma unroll
                for (int j = 0; j < 8; ++j) { vk[j] = bfc(pk[j]); vq[j] = bfc(pq[j]); }
                wfk[nt][kk] = vk; wfq[nt][kk] = vq;
            }
        for (int rt = 0; rt < 2; ++rt) {
            const int rbase = r0 + rt * 128 + w * 16;
            for (int t = 0; t < 2; ++t) {
                const float* X = t ? qry : keys;
                short8 a[2];
#pragma unroll
                for (int kk = 0; kk < 2; ++kk) {
                    const float* p = X + (size_t)(rbase + c) * DD + kk * 32 + g * 8;
                    short8 v;
#pragma unroll
                    for (int j = 0; j < 8; ++j) v[j] = bfc(p[j]);
                    a[kk] = v;
                }
#pragma unroll
                for (int nt = 0; nt < 4; ++nt) {
                    f32x4 acc = {0.f, 0.f, 0.f, 0.f};
                    acc = mfma16(a[0], t ? wfq[nt][0] : wfk[nt][0], acc);
                    acc = mfma16(a[1], t ? wfq[nt][1] : wfk[nt][1], acc);
#pragma unroll
                    for (int reg = 0; reg < 4; ++reg) {
                        int r = rbase + g * 4 + reg;
                        int h = r & 7, l = (r >> 3) & (LL - 1);
                        int o = nt * 16 + c;
                        size_t idx = ((size_t)(n * HH + h) * LL + l) * DD + o;
                        if (t) Qp[idx] = (unsigned short)bfc(acc[reg] *
                                  (0.04419417382415922f * 1.4426950408889634f));
                        else   Kp[idx] = (unsigned short)bfc(acc[reg]);
                    }
                }
            }
        }
    }
}

// ---------------------------------------------------------------- K2 staging helper
// Stage a 64x64 bf16 tile (row stride rstride elems) into LDS via global_load_lds,
// with the XOR bank swizzle ((row&7) on 16B chunks) folded into the source address.
static __device__ __forceinline__ void stage_tile(const unsigned short* __restrict__ src,
                                                  unsigned short* buf, int w, int ln,
                                                  size_t rstride) {
#pragma unroll
    for (int r = 0; r < 2; ++r) {
        int qi = w * 2 + r;
        int row = qi * 8 + (ln >> 3);
        int s = (ln & 7) ^ (row & 7);
        __builtin_amdgcn_global_load_lds(
            (const __attribute__((address_space(1))) unsigned int*)(src + (size_t)row * rstride + s * 8),
            (__attribute__((address_space(3))) unsigned int*)(buf + qi * 512),
            16, 0, 0);
    }
}

// ---------------------------------------------------------------- K2: causal flash attention
// grid 512 blocks, 4 waves. XCD-local mapping: XCD x8 = b&7 serves heads 4*x8..4*x8+3
// (K+V = 2MB, L2-resident). Blocks b and b+256: same XCD, same head, complementary
// q-chunks i and 15-i (work sums to 36 iters -> balanced 2-resident pairs).
__global__ __launch_bounds__(256) void k_attn(const unsigned short* __restrict__ Qp,
                                              const unsigned short* __restrict__ Kp,
                                              const unsigned short* __restrict__ Vg,
                                              unsigned short* __restrict__ Xa) {
    __shared__ __align__(16) unsigned short Kt[2][64 * 64];  // [kv][d], swz ((kv&7)<<4)
    __shared__ __align__(16) unsigned short Vt[2][64 * 64];  // [d][kv], swz ((d&7)<<4)

    const int tid = threadIdx.x;
    const int w = tid >> 6, ln = tid & 63;
    const int c31 = ln & 31, g2 = ln >> 5;

    const int b = blockIdx.x;
    const int x8 = b & 7;
    const int idx = b >> 3;
    const int nh = (x8 << 2) | (idx & 3);
    const int ii = (idx >> 2) & 7;
    const int i = (idx >> 5) ? ii : 15 - ii;
    const int qt = 4 * i + w;
    const int Q0 = qt * 32;
    const int nIter = 2 * i + 2;

    const unsigned short* Qb = Qp + (size_t)nh * (LL * DD);
    const unsigned short* Kb = Kp + (size_t)nh * (LL * DD);
    const unsigned short* Vb = Vg + (size_t)nh * (LL * DD);   // tiled [l>>6][d][l&63]

    // Q fragments (B-operand: col=q=c31, k = kc*16 + 8*g2 + j)
    short8 qf[4];
#pragma unroll
    for (int kc = 0; kc < 4; ++kc)
        qf[kc] = *(const short8*)(Qb + (Q0 + c31) * DD + kc * 16 + g2 * 8);

    f32x16 oacc0, oacc1;
#pragma unroll
    for (int r = 0; r < 16; ++r) { oacc0[r] = 0.f; oacc1[r] = 0.f; }
    float m = -1e30f, lsum = 0.f;

    // prologue: stage tile 0
    stage_tile(Kb, &Kt[0][0], w, ln, DD);
    stage_tile(Vb, &Vt[0][0], w, ln, 64);
    __syncthreads();

    int cur = 0;
    for (int t = 0; t < nIter; ++t) {
        const int nxt = cur ^ 1;
        if (t + 1 < nIter) {   // prefetch next tile (drained by end-of-iter barrier)
            stage_tile(Kb + (size_t)(t + 1) * (64 * DD), &Kt[nxt][0], w, ln, DD);
            stage_tile(Vb + (size_t)(t + 1) * 4096, &Vt[nxt][0], w, ln, 64);
        }

        if (t * 64 <= Q0 + 31) {    // wave-active tile
            const char* kb_ = (const char*)&Kt[cur][0];
            const char* vb_ = (const char*)&Vt[cur][0];
            const bool act1 = (t * 64 + 32 <= Q0 + 31);
            const int q = Q0 + c31;

            // ---- QK^T: S^T[kv][q] for 64 kv (lane owns q-row = c31)
            f32x16 sc0, sc1;
#pragma unroll
            for (int r = 0; r < 16; ++r) { sc0[r] = 0.f; sc1[r] = 0.f; }
            {
                const int R = c31;
                const unsigned rb = (unsigned)(R * 128);
                const unsigned swz = (unsigned)((R & 7) << 4);
#pragma unroll
                for (int kc = 0; kc < 4; ++kc) {
                    short8 af = *(const short8*)(kb_ + rb + (((unsigned)(kc * 32 + g2 * 16)) ^ swz));
                    sc0 = mfma32(af, qf[kc], sc0);
                }
            }
            if (act1) {
                const int R = 32 + c31;
                const unsigned rb = (unsigned)(R * 128);
                const unsigned swz = (unsigned)((R & 7) << 4);
#pragma unroll
                for (int kc = 0; kc < 4; ++kc) {
                    short8 af = *(const short8*)(kb_ + rb + (((unsigned)(kc * 32 + g2 * 16)) ^ swz));
                    sc1 = mfma32(af, qf[kc], sc1);
                }
            }

            // ---- causal mask on the diagonal subtiles
            if (t * 64 + 31 > Q0) {
#pragma unroll
                for (int r = 0; r < 16; ++r) {
                    int kvg = t * 64 + (r & 3) + 8 * (r >> 2) + 4 * g2;
                    sc0[r] = (kvg > q) ? -1e30f : sc0[r];
                }
            }
            if (act1 && t * 64 + 63 > Q0) {
#pragma unroll
                for (int r = 0; r < 16; ++r) {
                    int kvg = t * 64 + 32 + (r & 3) + 8 * (r >> 2) + 4 * g2;
                    sc1[r] = (kvg > q) ? -1e30f : sc1[r];
                }
            }

            // ---- one online-softmax round over up to 64 kv (exp2 domain)
            float tm;
            {
                float a[8];
#pragma unroll
                for (int r = 0; r < 8; ++r) a[r] = fmaxf(sc0[r], sc0[r + 8]);
                if (act1) {
#pragma unroll
                    for (int r = 0; r < 8; ++r)
                        a[r] = fmaxf(a[r], fmaxf(sc1[r], sc1[r + 8]));
                }
                float b0 = fmaxf(a[0], a[4]), b1 = fmaxf(a[1], a[5]);
                float b2 = fmaxf(a[2], a[6]), b3 = fmaxf(a[3], a[7]);
                tm = fmaxf(fmaxf(b0, b1), fmaxf(b2, b3));
            }
            tm = fmaxf(tm, __shfl_xor(tm, 32));

            // defer-max: only rescale when running max grew by > 6 (log2 units)
            if (!__all(tm <= m + 6.0f)) {
                float mn = fmaxf(m, tm);
                float corr = EXP2(m - mn);
                m = mn;
                lsum *= corr;
#pragma unroll
                for (int r = 0; r < 16; ++r) { oacc0[r] *= corr; oacc1[r] *= corr; }
            }

#pragma unroll
            for (int r = 0; r < 16; ++r) sc0[r] = EXP2(sc0[r] - m);
            if (act1) {
#pragma unroll
                for (int r = 0; r < 16; ++r) sc1[r] = EXP2(sc1[r] - m);
            }
            {
                float a[8];
#pragma unroll
                for (int r = 0; r < 8; ++r) a[r] = sc0[r] + sc0[r + 8];
                if (act1) {
#pragma unroll
                    for (int r = 0; r < 8; ++r) a[r] += sc1[r] + sc1[r + 8];
                }
                float b0 = a[0] + a[4], b1 = a[1] + a[5];
                float b2 = a[2] + a[6], b3 = a[3] + a[7];
                float ts = (b0 + b1) + (b2 + b3);
                ts += __shfl_xor(ts, 32);
                lsum += ts;
            }

            // ---- PV per 32-kv subtile: pack P to bf16, exchange halves, 4 MFMA
#pragma unroll
            for (int st = 0; st < 2; ++st) {
                if (st == 1 && !act1) break;
                const f32x16& sc = st ? sc1 : sc0;
                unsigned pk[8];
#pragma unroll
                for (int iw = 0; iw < 8; ++iw) pk[iw] = pkbf(sc[2 * iw], sc[2 * iw + 1]);
#pragma unroll
                for (int ck = 0; ck < 2; ++ck) {
                    unsigned s0 = g2 ? pk[4 * ck + 0] : pk[4 * ck + 2];
                    unsigned s1 = g2 ? pk[4 * ck + 1] : pk[4 * ck + 3];
                    unsigned x0 = __shfl_xor(s0, 32);
                    unsigned x1 = __shfl_xor(s1, 32);
                    u32x4 bfv;
                    bfv[0] = g2 ? x0 : pk[4 * ck + 0];
                    bfv[1] = g2 ? x1 : pk[4 * ck + 1];
                    bfv[2] = g2 ? pk[4 * ck + 2] : x0;
                    bfv[3] = g2 ? pk[4 * ck + 3] : x1;
                    short8 pB = __builtin_bit_cast(short8, bfv);
                    const unsigned coff = (unsigned)(st * 64 + ck * 32 + g2 * 16);
                    {
                        const int dP = c31;
                        short8 A = *(const short8*)(vb_ + (unsigned)(dP * 128) +
                                                    (coff ^ ((unsigned)((dP & 7) << 4))));
                        oacc0 = mfma32(A, pB, oacc0);
                    }
                    {
                        const int dP = 32 + c31;
                        short8 A = *(const short8*)(vb_ + (unsigned)(dP * 128) +
                                                    (coff ^ ((unsigned)((dP & 7) << 4))));
                        oacc1 = mfma32(A, pB, oacc1);
                    }
                }
            }
        }

        __syncthreads();
        cur = nxt;
    }

    // ---- epilogue: O = O^T normalized, store bf16 [n, l, h*64 + d]
    const float inv = 1.0f / lsum;
    const int n = nh >> 3, h = nh & 7;
    unsigned short* orow = Xa + ((size_t)(n * LL + Q0 + c31)) * EE + h * DD;
#pragma unroll
    for (int a = 0; a < 4; ++a) {
        {
            float e0 = oacc0[4 * a + 0] * inv, e1 = oacc0[4 * a + 1] * inv;
            float e2 = oacc0[4 * a + 2] * inv, e3 = oacc0[4 * a + 3] * inv;
            uint2 u = {pkbf(e0, e1), pkbf(e2, e3)};
            *(uint2*)(orow + a * 8 + g2 * 4) = u;
        }
        {
            float e0 = oacc1[4 * a + 0] * inv, e1 = oacc1[4 * a + 1] * inv;
            float e2 = oacc1[4 * a + 2] * inv, e3 = oacc1[4 * a + 3] * inv;
            uint2 u = {pkbf(e0, e1), pkbf(e2, e3)};
            *(uint2*)(orow + 32 + a * 8 + g2 * 4) = u;
        }
    }
}

// ---------------------------------------------------------------- K3: out = X @ Wo^T + bo (fp32)
// 512 blocks 1D. XCD x8 = b&7 owns M-band 8*x8..8*x8+7 (A 1MB + Wo 0.5MB L2-resident).
// Block = 128 M x 64 N; wave computes two 16x64 tiles sharing B fragments.
__global__ __launch_bounds__(256) void k_out(const unsigned short* __restrict__ X,
                                             const unsigned short* __restrict__ Wob,
                                             const float* __restrict__ bo,
                                             float* __restrict__ out) {
    const int tid = threadIdx.x, w = tid >> 6, ln = tid & 63, c = ln & 15, g = ln >> 4;
    const int b = blockIdx.x;
    const int x8 = b & 7, jj = b >> 3;
    const int mb = x8 * 8 + (jj & 7);   // 0..63, 128-row tiles
    const int nb = jj >> 3;             // 0..7,  64-col tiles
    const int mbase = mb * 128 + w * 16;
    const int nbase = nb * 64;

    f32x4 acc0[4] = {}, acc1[4] = {};
    for (int ks = 0; ks < 16; ++ks) {
        short8 a0 = *(const short8*)(X + (size_t)(mbase + c) * EE + ks * 32 + g * 8);
        short8 a1 = *(const short8*)(X + (size_t)(mbase + 64 + c) * EE + ks * 32 + g * 8);
#pragma unroll
        for (int nt = 0; nt < 4; ++nt) {
            short8 bfr = *(const short8*)(Wob + (size_t)(nbase + nt * 16 + c) * EE + ks * 32 + g * 8);
            acc0[nt] = mfma16(a0, bfr, acc0[nt]);
            acc1[nt] = mfma16(a1, bfr, acc1[nt]);
        }
    }
#pragma unroll
    for (int nt = 0; nt < 4; ++nt) {
        float bias = bo[nbase + nt * 16 + c];
#pragma unroll
        for (int reg = 0; reg < 4; ++reg) {
            int row0 = mbase + g * 4 + reg;
            out[(size_t)row0 * EE + nbase + nt * 16 + c] = acc0[nt][reg] + bias;
            out[(size_t)(row0 + 64) * EE + nbase + nt * 16 + c] = acc1[nt][reg] + bias;
        }
    }
}

// ---------------------------------------------------------------- launch
extern "C" void kernel_launch(void* const* d_in, const int* in_sizes, int n_in,
                              void* d_out, int out_size, void* d_ws, size_t ws_size,
                              hipStream_t stream) {
    const float* vals = (const float*)d_in[0];
    const float* keys = (const float*)d_in[1];
    const float* qry  = (const float*)d_in[2];
    // d_in[3] = causal mask (constant tril, analytic in k_attn)
    const float* Wv = (const float*)d_in[4];
    const float* Wk = (const float*)d_in[5];
    const float* Wq = (const float*)d_in[6];
    const float* Wo = (const float*)d_in[7];
    const float* bo = (const float*)d_in[8];
    float* out = (float*)d_out;

    char* ws = (char*)d_ws;
    unsigned short* Qp  = (unsigned short*)(ws);                  // 8 MB  [n,h,l,d]
    unsigned short* Kp  = (unsigned short*)(ws + (8u  << 20));    // 8 MB  [n,h,l,d]
    unsigned short* Vg  = (unsigned short*)(ws + (16u << 20));    // 8 MB  [nh][l/64][d][l%64]
    unsigned short* Xa  = (unsigned short*)(ws + (24u << 20));    // 8 MB  [n,l,e]
    unsigned short* Wob = (unsigned short*)(ws + (32u << 20));    // 0.5 MB

    hipLaunchKernelGGL(k_cvt, dim3(256), dim3(256), 0, stream, Wo, Wob, EE * EE);
    hipLaunchKernelGGL(k_proj, dim3(256), dim3(512), 0, stream,
                       vals, keys, qry, Wv, Wk, Wq, Qp, Kp, Vg);
    hipLaunchKernelGGL(k_attn, dim3(512), dim3(256), 0, stream, Qp, Kp, Vg, Xa);
    hipLaunchKernelGGL(k_out, dim3(512), dim3(256), 0, stream, Xa, Wob, bo, out);
}